// Round 6
// baseline (345.509 us; speedup 1.0000x reference)
//
#include <hip/hip_runtime.h>

// SplineCNN on MI355X.
// Sparse edge extraction (adj ~6% dense, basis shared across layers);
// per-layer: split-bf16 MFMA GEMM [B*N,3K]x[3K,640] -> sparse aggregate
// (+root+bias+relu, emits next layer's split-bf16 input).
// hw is stored bf16-packed [m][kx][f][slot4] slots={v(ky0),v(ky1),v(ky1),v(ky2)}
// so each edge needs only 2 aligned dword gathers (ky-pair per kx row).
// Root slice kept fp32 in separate coalesced buffer.
// Aggregate: XCD-swizzled grid (L2 locality), LDS-staged edge lists, x8 unroll.
// Layer-2 aggregate fuses global max-pool via uint-bitcast atomicMax (relu >= 0).

#define B_   32
#define N_   512
#define F_   64
#define CAP  128          // max neighbors per node (mean ~31, 128 is >>6 sigma)
#define NCOL 640          // 9*F (spline kernels) + F (root)

typedef short bf16x8 __attribute__((ext_vector_type(8)));
typedef float f32x4  __attribute__((ext_vector_type(4)));

__device__ __forceinline__ unsigned short to_bf16_rne(float v) {
  unsigned u = __float_as_uint(v);
  unsigned r = u + 0x7fffu + ((u >> 16) & 1u);
  return (unsigned short)(r >> 16);
}
__device__ __forceinline__ float bf16_to_f(unsigned short h) {
  return __uint_as_float(((unsigned)h) << 16);
}

// ---------------- preprocess: edge lists + factored spline basis ----------------
// edge record: float4 { bitcast(m*384 + kx0*128 + ky0), fx, fy, 1.0 }
// (w=1 marks valid; zero records give all-zero tap weights and base 0)
__global__ __launch_bounds__(512) void preprocess_kernel(
    const float* __restrict__ adj, const float* __restrict__ coord,
    float4* __restrict__ edge, int* __restrict__ cnt_out,
    float* __restrict__ deginv_out) {
  int row = blockIdx.x;          // b*N + n
  int b = row >> 9;
  int tid = threadIdx.x;         // == m (within batch)
  int lane = tid & 63, wave = tid >> 6;
  __shared__ int wcnt[8];
  float a = adj[(size_t)row * N_ + tid];
  bool flag = (a != 0.0f);
  unsigned long long ball = __ballot(flag);
  if (lane == 0) wcnt[wave] = __popcll(ball);
  __syncthreads();
  int woff = 0, total = 0;
  #pragma unroll
  for (int i = 0; i < 8; ++i) { int c = wcnt[i]; if (i < wave) woff += c; total += c; }
  if (flag) {
    int pos = woff + __popcll(ball & ((1ULL << lane) - 1));
    if (pos < CAP) {
      int m = tid;
      float cxn = coord[(size_t)row * 2 + 0];
      float cyn = coord[(size_t)row * 2 + 1];
      float cxm = coord[(size_t)(b * N_ + m) * 2 + 0];
      float cym = coord[(size_t)(b * N_ + m) * 2 + 1];
      float vx = (cxm - cxn + 1.0f) * 0.5f * 2.0f;
      float vy = (cym - cyn + 1.0f) * 0.5f * 2.0f;
      float i0x = fminf(fmaxf(floorf(vx), 0.0f), 1.0f);
      float i0y = fminf(fmaxf(floorf(vy), 0.0f), 1.0f);
      float fx = vx - i0x, fy = vy - i0y;
      int kx0 = (int)i0x, ky0 = (int)i0y;
      int ebase = m * 384 + kx0 * 128 + ky0;   // dword index into packed hw (per batch)
      edge[(size_t)row * CAP + pos] =
          make_float4(__int_as_float(ebase), fx, fy, 1.0f);
    }
  }
  if (tid == 0) {
    cnt_out[row] = total > CAP ? CAP : total;
    deginv_out[row] = 1.0f / (float)(total > 0 ? total : 1);
  }
}

// ---------------- convert x (fp32 [M,128]) -> split-bf16 A [M, 384] ----------------
__global__ void convx_kernel(const float* __restrict__ x, unsigned short* __restrict__ a) {
  int idx = blockIdx.x * blockDim.x + threadIdx.x;
  if (idx >= B_ * N_ * 128) return;
  int row = idx >> 7, k = idx & 127;
  float v = x[idx];
  unsigned short hi = to_bf16_rne(v);
  unsigned short lo = to_bf16_rne(v - bf16_to_f(hi));
  size_t base = (size_t)row * 384;
  a[base + k] = hi;
  a[base + 128 + k] = lo;
  a[base + 256 + k] = hi;
}

// ---- pack w (9 slices)+root -> W^T split-bf16 [640 n][3*cin k'] (slabs hi,hi,lo) ----
__global__ void packw_kernel(const float* __restrict__ w, const float* __restrict__ root,
                             int cin, unsigned short* __restrict__ wt) {
  int idx = blockIdx.x * blockDim.x + threadIdx.x;
  int total = NCOL * cin;
  if (idx >= total) return;
  int n = idx / cin, k = idx - n * cin;
  int kk = n >> 6, f = n & 63;
  float v = (kk < 9) ? w[((size_t)kk * cin + k) * F_ + f]
                     : root[(size_t)k * F_ + f];
  unsigned short hi = to_bf16_rne(v);
  unsigned short lo = to_bf16_rne(v - bf16_to_f(hi));
  size_t base = (size_t)n * (3 * cin);
  wt[base + k] = hi;
  wt[base + cin + k] = hi;
  wt[base + 2 * cin + k] = lo;
}

// ---------------- split-bf16 MFMA GEMM -> packed-bf16 hw + fp32 root ----------------
// 128x128 tile, 256 threads = 4 waves (2x2 of 64x64), 16x16x32 bf16 MFMA, BK=64.
// LDS rows padded +8 bf16 (stride 144B -> conflict-free b128 frag reads).
// Epilogue scatters spline slices (kk<9) into hwpk [m][kx][f][slot4] bf16
// (slot0=ky0, slot1=slot2=ky1, slot3=ky2), root slice (kk==9) -> hwroot fp32.
#define BK 64
#define LDK (BK + 8)
__global__ __launch_bounds__(256) void gemm_mfma_kernel(
    const unsigned short* __restrict__ A,   // [M][KP]
    const unsigned short* __restrict__ Wt,  // [640][KP]  (W^T, n-major)
    unsigned short* __restrict__ hwpk,      // [M][3][64][4] bf16
    float* __restrict__ hwroot,             // [M][64] fp32
    int KP) {
  __shared__ unsigned short As[128 * LDK];
  __shared__ unsigned short Ws[128 * LDK];
  int bm = blockIdx.x * 128;
  int bn = blockIdx.y * 128;
  int tid = threadIdx.x;
  int wave = tid >> 6, lane = tid & 63;
  int mw = (wave & 1) * 64, nw = (wave >> 1) * 64;
  int lr = lane & 15, quad = lane >> 4;

  f32x4 acc[4][4] = {};
  for (int k0 = 0; k0 < KP; k0 += BK) {
    #pragma unroll
    for (int i = 0; i < 4; ++i) {
      int c = tid + i * 256;            // 0..1023 chunks of 16B
      int row = c >> 3, ck = (c & 7) * 8;
      *(float4*)&As[row * LDK + ck] =
          *(const float4*)&A[(size_t)(bm + row) * KP + k0 + ck];
      *(float4*)&Ws[row * LDK + ck] =
          *(const float4*)&Wt[(size_t)(bn + row) * KP + k0 + ck];
    }
    __syncthreads();
    #pragma unroll
    for (int kk = 0; kk < BK; kk += 32) {
      bf16x8 af[4], bf[4];
      #pragma unroll
      for (int i = 0; i < 4; ++i)
        af[i] = *(const bf16x8*)&As[(mw + 16 * i + lr) * LDK + kk + quad * 8];
      #pragma unroll
      for (int j = 0; j < 4; ++j)
        bf[j] = *(const bf16x8*)&Ws[(nw + 16 * j + lr) * LDK + kk + quad * 8];
      #pragma unroll
      for (int i = 0; i < 4; ++i)
        #pragma unroll
        for (int j = 0; j < 4; ++j)
          acc[i][j] = __builtin_amdgcn_mfma_f32_16x16x32_bf16(af[i], bf[j], acc[i][j], 0, 0, 0);
    }
    __syncthreads();
  }
  // epilogue: C/D layout col=lane&15, row=quad*4+reg (m89-verified).
  // kk = n>>6 is uniform across the wave for fixed j (n-base multiple of 16).
  #pragma unroll
  for (int j = 0; j < 4; ++j) {
    int n = bn + nw + 16 * j + lr;
    int kk = n >> 6;
    int f = n & 63;
    if (kk < 9) {
      int kx = kk / 3, ky = kk - kx * 3;
      #pragma unroll
      for (int i = 0; i < 4; ++i)
        #pragma unroll
        for (int r = 0; r < 4; ++r) {
          int m = bm + mw + 16 * i + quad * 4 + r;
          unsigned short hv = to_bf16_rne(acc[i][j][r]);
          size_t base = (size_t)m * 768 + kx * 256 + f * 4;
          if (ky == 0) {
            hwpk[base + 0] = hv;
          } else if (ky == 1) {
            hwpk[base + 1] = hv; hwpk[base + 2] = hv;
          } else {
            hwpk[base + 3] = hv;
          }
        }
    } else {
      #pragma unroll
      for (int i = 0; i < 4; ++i)
        #pragma unroll
        for (int r = 0; r < 4; ++r) {
          int m = bm + mw + 16 * i + quad * 4 + r;
          hwroot[(size_t)m * 64 + f] = acc[i][j][r];
        }
    }
  }
}

// ---------------- sparse aggregate (packed-bf16 hw) ----------------
// 256 threads = 4 waves, one row per wave. XCD-swizzled (blockIdx&7 = XCD).
// Edge lists staged to LDS, padded to x8 with zero records.
// Per edge: 2 dword gathers (ky-pair at kx0 and kx0+1), 16 loads in flight.
__global__ __launch_bounds__(256) void aggregate_kernel(
    const unsigned int* __restrict__ hwpk,   // dword view of [M][3][64][4] bf16
    const float* __restrict__ hwroot,
    const float4* __restrict__ edge,
    const int* __restrict__ cnt, const float* __restrict__ deginv,
    const float* __restrict__ bias,
    unsigned short* __restrict__ aout,
    unsigned int* __restrict__ gmax) {
  __shared__ float4 esh[4][CAP];
  int wave = threadIdx.x >> 6;
  int lane = threadIdx.x & 63;
  int f = lane;
  int xcd = blockIdx.x & 7;
  int j = blockIdx.x >> 3;
  int b = xcd * 4 + (j >> 7);
  int row = b * N_ + ((j & 127) << 2) + wave;
  int c = cnt[row];
  int cpad = (c + 7) & ~7;
  size_t ebase = (size_t)row * CAP;
  for (int i = lane; i < cpad; i += 64)
    esh[wave][i] = (i < c) ? edge[ebase + i] : make_float4(0.f, 0.f, 0.f, 0.f);
  __syncthreads();

  float di = deginv[row];
  const unsigned int* pk = hwpk + (size_t)b * (N_ * 384) + f * 2;
  float accs[4] = {0.f, 0.f, 0.f, 0.f};
  for (int e0 = 0; e0 < cpad; e0 += 8) {
    int bofs[8]; float ex1[8], ey1[8], vw[8];
    #pragma unroll
    for (int q = 0; q < 8; ++q) {
      float4 er = esh[wave][e0 + q];
      bofs[q] = __float_as_int(er.x);
      ex1[q] = er.y; ey1[q] = er.z; vw[q] = er.w;
    }
    unsigned int u0[8], u1[8];
    #pragma unroll
    for (int q = 0; q < 8; ++q) {
      u0[q] = pk[bofs[q]];
      u1[q] = pk[bofs[q] + 128];
    }
    #pragma unroll
    for (int q = 0; q < 8; ++q) {
      float vy0a = __uint_as_float(u0[q] << 16);
      float vy1a = __uint_as_float(u0[q] & 0xffff0000u);
      float vy0b = __uint_as_float(u1[q] << 16);
      float vy1b = __uint_as_float(u1[q] & 0xffff0000u);
      float ey0 = vw[q] - ey1[q];
      float ex0 = vw[q] - ex1[q];
      float t0 = ey0 * vy0a + ey1[q] * vy1a;
      float t1 = ey0 * vy0b + ey1[q] * vy1b;
      accs[q & 3] += ex0 * t0 + ex1[q] * t1;
    }
  }
  float rootv = hwroot[(size_t)row * 64 + f];
  float val = fmaxf(((accs[0] + accs[1]) + (accs[2] + accs[3])) * di + rootv + bias[f], 0.0f);
  if (aout) {
    unsigned short hi = to_bf16_rne(val);
    unsigned short lo = to_bf16_rne(val - bf16_to_f(hi));
    size_t base = (size_t)row * 192;
    aout[base + f] = hi;
    aout[base + 64 + f] = lo;
    aout[base + 128 + f] = hi;
  }
  if (gmax) {
    // relu output >= 0 -> IEEE bits monotone under unsigned compare
    atomicMax(&gmax[b * F_ + f], __float_as_uint(val));
  }
}

// ---------------- zero the pooled-max buffer ----------------
__global__ void zerog_kernel(unsigned int* __restrict__ g) {
  int i = blockIdx.x * blockDim.x + threadIdx.x;
  if (i < B_ * F_) g[i] = 0u;
}

// ---------------- FC from pooled features ----------------
__global__ __launch_bounds__(64) void fc_kernel(
    const float* __restrict__ g, const float* __restrict__ fcw,
    const float* __restrict__ fcb, float* __restrict__ out) {
  int b = blockIdx.x;
  int f = threadIdx.x;
  __shared__ float gs[64];
  gs[f] = g[b * F_ + f];
  __syncthreads();
  if (f < 10) {
    float s = fcb[f];
    #pragma unroll
    for (int c = 0; c < 64; ++c) s += gs[c] * fcw[c * 10 + f];
    out[b * 10 + f] = s;
  }
}

extern "C" void kernel_launch(void* const* d_in, const int* in_sizes, int n_in,
                              void* d_out, int out_size, void* d_ws, size_t ws_size,
                              hipStream_t stream) {
  const float* x     = (const float*)d_in[0];
  const float* coord = (const float*)d_in[1];
  const float* adj   = (const float*)d_in[2];
  const float* w0    = (const float*)d_in[3];
  const float* root0 = (const float*)d_in[4];
  const float* b0    = (const float*)d_in[5];
  const float* w1    = (const float*)d_in[6];
  const float* root1 = (const float*)d_in[7];
  const float* b1    = (const float*)d_in[8];
  const float* w2    = (const float*)d_in[9];
  const float* root2 = (const float*)d_in[10];
  const float* b2    = (const float*)d_in[11];
  const float* fcw   = (const float*)d_in[12];
  const float* fcb   = (const float*)d_in[13];
  float* out = (float*)d_out;

  char* ws = (char*)d_ws;
  size_t off = 0;
  auto alloc = [&](size_t bytes) {
    void* p = ws + off;
    off = (off + bytes + 255) & ~(size_t)255;
    return p;
  };
  const int R = B_ * N_;  // 16384
  float4* edge    = (float4*)alloc((size_t)R * CAP * 16);
  int*    cnt     = (int*)   alloc((size_t)R * 4);
  float*  deginv  = (float*) alloc((size_t)R * 4);
  unsigned short* abf0 = (unsigned short*)alloc((size_t)R * 384 * 2);
  unsigned short* abfN = (unsigned short*)alloc((size_t)R * 192 * 2);
  unsigned short* wt   = (unsigned short*)alloc((size_t)NCOL * 384 * 2);
  unsigned short* hwpk = (unsigned short*)alloc((size_t)R * 768 * 2);
  float*  hwroot  = (float*) alloc((size_t)R * 64 * 4);
  unsigned int* gmax = (unsigned int*)alloc((size_t)B_ * F_ * 4);

  preprocess_kernel<<<R, 512, 0, stream>>>(adj, coord, edge, cnt, deginv);
  zerog_kernel<<<(B_ * F_ + 255) / 256, 256, 0, stream>>>(gmax);
  convx_kernel<<<(R * 128 + 255) / 256, 256, 0, stream>>>(x, abf0);

  // layer 0 (Cin=128, KP=384)
  packw_kernel<<<(NCOL * 128 + 255) / 256, 256, 0, stream>>>(w0, root0, 128, wt);
  gemm_mfma_kernel<<<dim3(R / 128, NCOL / 128), 256, 0, stream>>>(abf0, wt, hwpk, hwroot, 384);
  aggregate_kernel<<<R / 4, 256, 0, stream>>>((const unsigned int*)hwpk, hwroot, edge, cnt, deginv, b0, abfN, nullptr);

  // layer 1 (Cin=64, KP=192)
  packw_kernel<<<(NCOL * 64 + 255) / 256, 256, 0, stream>>>(w1, root1, 64, wt);
  gemm_mfma_kernel<<<dim3(R / 128, NCOL / 128), 256, 0, stream>>>(abfN, wt, hwpk, hwroot, 192);
  aggregate_kernel<<<R / 4, 256, 0, stream>>>((const unsigned int*)hwpk, hwroot, edge, cnt, deginv, b1, abfN, nullptr);

  // layer 2 (Cin=64, KP=192) — fused max-pool
  packw_kernel<<<(NCOL * 64 + 255) / 256, 256, 0, stream>>>(w2, root2, 64, wt);
  gemm_mfma_kernel<<<dim3(R / 128, NCOL / 128), 256, 0, stream>>>(abfN, wt, hwpk, hwroot, 192);
  aggregate_kernel<<<R / 4, 256, 0, stream>>>((const unsigned int*)hwpk, hwroot, edge, cnt, deginv, b2, nullptr, gmax);

  fc_kernel<<<B_, 64, 0, stream>>>((const float*)gmax, fcw, fcb, out);
}

// Round 7
// 317.571 us; speedup vs baseline: 1.0880x; 1.0880x over previous
//
#include <hip/hip_runtime.h>

// SplineCNN on MI355X.
// Sparse edge extraction (adj ~6% dense, basis shared across layers);
// per-layer: split-bf16 MFMA GEMM [B*N,3K]x[3K,640] -> fp32 hw -> sparse aggregate
// (+root+bias+relu, emits next layer's split-bf16 input).
// Aggregate: XCD-swizzled grid (L2 locality), LDS-staged edge lists,
// 2 waves per row (edge-split, LDS partial combine), x8 unroll -> 32 gathers in flight.
// Layer-2 aggregate fuses global max-pool via uint-bitcast atomicMax (relu >= 0).

#define B_   32
#define N_   512
#define F_   64
#define CAP  128          // max neighbors per node (mean ~31, 128 is >>6 sigma)
#define NCOL 640          // 9*F (spline kernels) + F (root)

typedef short bf16x8 __attribute__((ext_vector_type(8)));
typedef float f32x4  __attribute__((ext_vector_type(4)));

__device__ __forceinline__ unsigned short to_bf16_rne(float v) {
  unsigned u = __float_as_uint(v);
  unsigned r = u + 0x7fffu + ((u >> 16) & 1u);
  return (unsigned short)(r >> 16);
}
__device__ __forceinline__ float bf16_to_f(unsigned short h) {
  return __uint_as_float(((unsigned)h) << 16);
}

// ---------------- preprocess: edge lists + factored spline basis ----------------
// edge record: float4 { bitcast(m*640 + k0c*64), fx, fy, 1.0 }  (dword base into hw[b];
// w=1 marks valid; zero records give all-zero tap weights and base 0)
__global__ __launch_bounds__(512) void preprocess_kernel(
    const float* __restrict__ adj, const float* __restrict__ coord,
    float4* __restrict__ edge, int* __restrict__ cnt_out,
    float* __restrict__ deginv_out) {
  int row = blockIdx.x;          // b*N + n
  int b = row >> 9;
  int tid = threadIdx.x;         // == m (within batch)
  int lane = tid & 63, wave = tid >> 6;
  __shared__ int wcnt[8];
  float a = adj[(size_t)row * N_ + tid];
  bool flag = (a != 0.0f);
  unsigned long long ball = __ballot(flag);
  if (lane == 0) wcnt[wave] = __popcll(ball);
  __syncthreads();
  int woff = 0, total = 0;
  #pragma unroll
  for (int i = 0; i < 8; ++i) { int c = wcnt[i]; if (i < wave) woff += c; total += c; }
  if (flag) {
    int pos = woff + __popcll(ball & ((1ULL << lane) - 1));
    if (pos < CAP) {
      int m = tid;
      float cxn = coord[(size_t)row * 2 + 0];
      float cyn = coord[(size_t)row * 2 + 1];
      float cxm = coord[(size_t)(b * N_ + m) * 2 + 0];
      float cym = coord[(size_t)(b * N_ + m) * 2 + 1];
      float vx = (cxm - cxn + 1.0f) * 0.5f * 2.0f;
      float vy = (cym - cyn + 1.0f) * 0.5f * 2.0f;
      float i0x = fminf(fmaxf(floorf(vx), 0.0f), 1.0f);
      float i0y = fminf(fmaxf(floorf(vy), 0.0f), 1.0f);
      float fx = vx - i0x, fy = vy - i0y;
      int k0c = (int)i0x * 3 + (int)i0y;
      int ebase = m * NCOL + k0c * F_;   // dword index into hw[b]
      edge[(size_t)row * CAP + pos] =
          make_float4(__int_as_float(ebase), fx, fy, 1.0f);
    }
  }
  if (tid == 0) {
    cnt_out[row] = total > CAP ? CAP : total;
    deginv_out[row] = 1.0f / (float)(total > 0 ? total : 1);
  }
}

// ---------------- convert x (fp32 [M,128]) -> split-bf16 A [M, 384] ----------------
__global__ void convx_kernel(const float* __restrict__ x, unsigned short* __restrict__ a) {
  int idx = blockIdx.x * blockDim.x + threadIdx.x;
  if (idx >= B_ * N_ * 128) return;
  int row = idx >> 7, k = idx & 127;
  float v = x[idx];
  unsigned short hi = to_bf16_rne(v);
  unsigned short lo = to_bf16_rne(v - bf16_to_f(hi));
  size_t base = (size_t)row * 384;
  a[base + k] = hi;
  a[base + 128 + k] = lo;
  a[base + 256 + k] = hi;
}

// ---- pack w (9 slices)+root -> W^T split-bf16 [640 n][3*cin k'] (slabs hi,hi,lo) ----
__global__ void packw_kernel(const float* __restrict__ w, const float* __restrict__ root,
                             int cin, unsigned short* __restrict__ wt) {
  int idx = blockIdx.x * blockDim.x + threadIdx.x;
  int total = NCOL * cin;
  if (idx >= total) return;
  int n = idx / cin, k = idx - n * cin;
  int kk = n >> 6, f = n & 63;
  float v = (kk < 9) ? w[((size_t)kk * cin + k) * F_ + f]
                     : root[(size_t)k * F_ + f];
  unsigned short hi = to_bf16_rne(v);
  unsigned short lo = to_bf16_rne(v - bf16_to_f(hi));
  size_t base = (size_t)n * (3 * cin);
  wt[base + k] = hi;
  wt[base + cin + k] = hi;
  wt[base + 2 * cin + k] = lo;
}

// ---------------- split-bf16 MFMA GEMM: C[M,640] = A[M,KP] * Wt[640,KP]^T ----------------
// 64x128 tile (M x N), 256 threads = 4 waves (2x2), wave tile 32x64,
// 16x16x32 bf16 MFMA, BK=64. Grid 256x5 = 1280 blocks (5/CU).
// LDS rows padded +8 bf16 (stride 144B -> conflict-free b128 frag reads).
#define BK 64
#define LDK (BK + 8)
__global__ __launch_bounds__(256) void gemm_mfma_kernel(
    const unsigned short* __restrict__ A,   // [M][KP]
    const unsigned short* __restrict__ Wt,  // [640][KP]  (W^T, n-major)
    float* __restrict__ C, int KP) {
  __shared__ unsigned short As[64 * LDK];
  __shared__ unsigned short Ws[128 * LDK];
  int bm = blockIdx.x * 64;
  int bn = blockIdx.y * 128;
  int tid = threadIdx.x;
  int wave = tid >> 6, lane = tid & 63;
  int mw = (wave & 1) * 32, nw = (wave >> 1) * 64;
  int lr = lane & 15, quad = lane >> 4;

  f32x4 acc[2][4] = {};
  for (int k0 = 0; k0 < KP; k0 += BK) {
    #pragma unroll
    for (int i = 0; i < 2; ++i) {        // A tile: 64 rows x 64 k = 512 x 16B
      int c = tid + i * 256;
      int row = c >> 3, ck = (c & 7) * 8;
      *(float4*)&As[row * LDK + ck] =
          *(const float4*)&A[(size_t)(bm + row) * KP + k0 + ck];
    }
    #pragma unroll
    for (int i = 0; i < 4; ++i) {        // W tile: 128 rows x 64 k = 1024 x 16B
      int c = tid + i * 256;
      int row = c >> 3, ck = (c & 7) * 8;
      *(float4*)&Ws[row * LDK + ck] =
          *(const float4*)&Wt[(size_t)(bn + row) * KP + k0 + ck];
    }
    __syncthreads();
    #pragma unroll
    for (int kk = 0; kk < BK; kk += 32) {
      bf16x8 af[2], bf[4];
      #pragma unroll
      for (int i = 0; i < 2; ++i)
        af[i] = *(const bf16x8*)&As[(mw + 16 * i + lr) * LDK + kk + quad * 8];
      #pragma unroll
      for (int j = 0; j < 4; ++j)
        bf[j] = *(const bf16x8*)&Ws[(nw + 16 * j + lr) * LDK + kk + quad * 8];
      #pragma unroll
      for (int i = 0; i < 2; ++i)
        #pragma unroll
        for (int j = 0; j < 4; ++j)
          acc[i][j] = __builtin_amdgcn_mfma_f32_16x16x32_bf16(af[i], bf[j], acc[i][j], 0, 0, 0);
    }
    __syncthreads();
  }
  // epilogue: C/D layout col=lane&15, row=quad*4+reg (m89-verified)
  #pragma unroll
  for (int i = 0; i < 2; ++i)
    #pragma unroll
    for (int j = 0; j < 4; ++j)
      #pragma unroll
      for (int r = 0; r < 4; ++r) {
        int m = bm + mw + 16 * i + quad * 4 + r;
        int n = bn + nw + 16 * j + lr;
        C[(size_t)m * NCOL + n] = acc[i][j][r];
      }
}

// ---------------- sparse aggregate (fp32 hw, edge-split across 2 waves) ----------------
// 256 threads = 4 waves = 2 rows x 2 edge-halves. XCD-swizzled (blockIdx&7 = XCD).
// Edge lists staged to LDS (128 threads per row), padded to x8 with zero records.
// Each wave: 8 edges/iter x 4 taps = 32 gathers in flight; halves combine via LDS.
__global__ __launch_bounds__(256) void aggregate_kernel(
    const float* __restrict__ hw,
    const float4* __restrict__ edge,
    const int* __restrict__ cnt, const float* __restrict__ deginv,
    const float* __restrict__ bias,
    unsigned short* __restrict__ aout,
    unsigned int* __restrict__ gmax) {
  __shared__ float4 esh[2][CAP];
  __shared__ float psum[2][64];
  int tid = threadIdx.x;
  int wave = tid >> 6, f = tid & 63;
  int pair = wave >> 1;          // which row in block (0..1)
  int half = wave & 1;           // which edge half (0..1)
  int xcd = blockIdx.x & 7;
  int j = blockIdx.x >> 3;       // 0..1023
  int b = xcd * 4 + (j >> 8);    // 4 batches per XCD
  int row = b * N_ + ((j & 255) << 1) + pair;
  int c = cnt[row];
  int cpad = (c + 7) & ~7;
  size_t ebase = (size_t)row * CAP;
  int t128 = tid & 127;          // 128 threads per pair stage that row's edges
  for (int i = t128; i < cpad; i += 128)
    esh[pair][i] = (i < c) ? edge[ebase + i] : make_float4(0.f, 0.f, 0.f, 0.f);
  __syncthreads();

  const float* hwb = hw + (size_t)b * N_ * NCOL;
  float accs[4] = {0.f, 0.f, 0.f, 0.f};
  for (int e0 = half * 8; e0 < cpad; e0 += 16) {
    int off[8];
    float w00[8], w01[8], w10[8], w11[8];
    #pragma unroll
    for (int q = 0; q < 8; ++q) {
      float4 er = esh[pair][e0 + q];
      off[q] = __float_as_int(er.x) + f;
      float bx1 = er.y, by1 = er.z, v = er.w;
      float bx0 = v - bx1, by0 = v - by1;
      w00[q] = bx0 * by0; w01[q] = bx0 * by1;
      w10[q] = bx1 * by0; w11[q] = bx1 * by1;
    }
    float t0[8], t1[8], t2[8], t3[8];
    #pragma unroll
    for (int q = 0; q < 8; ++q) {
      const float* p = hwb + off[q];
      t0[q] = p[0]; t1[q] = p[F_]; t2[q] = p[3 * F_]; t3[q] = p[4 * F_];
    }
    #pragma unroll
    for (int q = 0; q < 8; ++q)
      accs[q & 3] += w00[q] * t0[q] + w01[q] * t1[q] + w10[q] * t2[q] + w11[q] * t3[q];
  }
  float part = (accs[0] + accs[1]) + (accs[2] + accs[3]);
  if (half == 1) psum[pair][f] = part;
  __syncthreads();
  if (half == 0) {
    float di = deginv[row];
    float total = part + psum[pair][f];
    float rootv = hwb[((size_t)row - (size_t)b * N_) * NCOL + 9 * F_ + f];
    float val = fmaxf(total * di + rootv + bias[f], 0.0f);
    if (aout) {
      unsigned short hi = to_bf16_rne(val);
      unsigned short lo = to_bf16_rne(val - bf16_to_f(hi));
      size_t base = (size_t)row * 192;
      aout[base + f] = hi;
      aout[base + 64 + f] = lo;
      aout[base + 128 + f] = hi;
    }
    if (gmax) {
      // relu output >= 0 -> IEEE bits monotone under unsigned compare
      atomicMax(&gmax[b * F_ + f], __float_as_uint(val));
    }
  }
}

// ---------------- zero the pooled-max buffer ----------------
__global__ void zerog_kernel(unsigned int* __restrict__ g) {
  int i = blockIdx.x * blockDim.x + threadIdx.x;
  if (i < B_ * F_) g[i] = 0u;
}

// ---------------- FC from pooled features ----------------
__global__ __launch_bounds__(64) void fc_kernel(
    const float* __restrict__ g, const float* __restrict__ fcw,
    const float* __restrict__ fcb, float* __restrict__ out) {
  int b = blockIdx.x;
  int f = threadIdx.x;
  __shared__ float gs[64];
  gs[f] = g[b * F_ + f];
  __syncthreads();
  if (f < 10) {
    float s = fcb[f];
    #pragma unroll
    for (int c = 0; c < 64; ++c) s += gs[c] * fcw[c * 10 + f];
    out[b * 10 + f] = s;
  }
}

extern "C" void kernel_launch(void* const* d_in, const int* in_sizes, int n_in,
                              void* d_out, int out_size, void* d_ws, size_t ws_size,
                              hipStream_t stream) {
  const float* x     = (const float*)d_in[0];
  const float* coord = (const float*)d_in[1];
  const float* adj   = (const float*)d_in[2];
  const float* w0    = (const float*)d_in[3];
  const float* root0 = (const float*)d_in[4];
  const float* b0    = (const float*)d_in[5];
  const float* w1    = (const float*)d_in[6];
  const float* root1 = (const float*)d_in[7];
  const float* b1    = (const float*)d_in[8];
  const float* w2    = (const float*)d_in[9];
  const float* root2 = (const float*)d_in[10];
  const float* b2    = (const float*)d_in[11];
  const float* fcw   = (const float*)d_in[12];
  const float* fcb   = (const float*)d_in[13];
  float* out = (float*)d_out;

  char* ws = (char*)d_ws;
  size_t off = 0;
  auto alloc = [&](size_t bytes) {
    void* p = ws + off;
    off = (off + bytes + 255) & ~(size_t)255;
    return p;
  };
  const int R = B_ * N_;  // 16384
  float4* edge    = (float4*)alloc((size_t)R * CAP * 16);
  int*    cnt     = (int*)   alloc((size_t)R * 4);
  float*  deginv  = (float*) alloc((size_t)R * 4);
  unsigned short* abf0 = (unsigned short*)alloc((size_t)R * 384 * 2);
  unsigned short* abfN = (unsigned short*)alloc((size_t)R * 192 * 2);
  unsigned short* wt   = (unsigned short*)alloc((size_t)NCOL * 384 * 2);
  float*  hw      = (float*) alloc((size_t)R * NCOL * 4);
  unsigned int* gmax = (unsigned int*)alloc((size_t)B_ * F_ * 4);

  preprocess_kernel<<<R, 512, 0, stream>>>(adj, coord, edge, cnt, deginv);
  zerog_kernel<<<(B_ * F_ + 255) / 256, 256, 0, stream>>>(gmax);
  convx_kernel<<<(R * 128 + 255) / 256, 256, 0, stream>>>(x, abf0);

  // layer 0 (Cin=128, KP=384)
  packw_kernel<<<(NCOL * 128 + 255) / 256, 256, 0, stream>>>(w0, root0, 128, wt);
  gemm_mfma_kernel<<<dim3(R / 64, NCOL / 128), 256, 0, stream>>>(abf0, wt, hw, 384);
  aggregate_kernel<<<R / 2, 256, 0, stream>>>(hw, edge, cnt, deginv, b0, abfN, nullptr);

  // layer 1 (Cin=64, KP=192)
  packw_kernel<<<(NCOL * 64 + 255) / 256, 256, 0, stream>>>(w1, root1, 64, wt);
  gemm_mfma_kernel<<<dim3(R / 64, NCOL / 128), 256, 0, stream>>>(abfN, wt, hw, 192);
  aggregate_kernel<<<R / 2, 256, 0, stream>>>(hw, edge, cnt, deginv, b1, abfN, nullptr);

  // layer 2 (Cin=64, KP=192) — fused max-pool
  packw_kernel<<<(NCOL * 64 + 255) / 256, 256, 0, stream>>>(w2, root2, 64, wt);
  gemm_mfma_kernel<<<dim3(R / 64, NCOL / 128), 256, 0, stream>>>(abfN, wt, hw, 192);
  aggregate_kernel<<<R / 2, 256, 0, stream>>>(hw, edge, cnt, deginv, b2, nullptr, gmax);

  fc_kernel<<<B_, 64, 0, stream>>>((const float*)gmax, fcw, fcb, out);
}

// Round 8
// 280.009 us; speedup vs baseline: 1.2339x; 1.1341x over previous
//
#include <hip/hip_runtime.h>

// SplineCNN on MI355X.
// Sparse edge extraction (adj ~6% dense, basis shared across layers);
// per-layer: split-bf16 MFMA GEMM [B*N,3K]x[3K,640] -> bf16 hw (+fp32 root) ->
// sparse aggregate (+root+bias+relu, emits next layer's split-bf16 input).
// hw taps stored plain bf16 [m][k][f]: each tap = wave-contiguous 128B ushort load
// (1 L2 line fully used) -> half the L2/HBM bytes of fp32, same dense-lane pattern.
// (Round-6 lesson: the slot-packed layout halved load COUNT but doubled touched
// lines via stride-2 lanes — plain bf16 halves BYTES with dense lanes.)
// Aggregate: XCD-swizzled grid (L2 locality), LDS-staged edge lists, 1 row/wave,
// x8 unroll -> 32 independent gathers in flight.
// Layer-2 aggregate fuses global max-pool via uint-bitcast atomicMax (relu >= 0).

#define B_   32
#define N_   512
#define F_   64
#define CAP  128          // max neighbors per node (mean ~31, 128 is >>6 sigma)
#define NCOL 640          // 9*F (spline kernels) + F (root)
#define HWC  576          // 9*F bf16 spline cols per row

typedef short bf16x8 __attribute__((ext_vector_type(8)));
typedef float f32x4  __attribute__((ext_vector_type(4)));

__device__ __forceinline__ unsigned short to_bf16_rne(float v) {
  unsigned u = __float_as_uint(v);
  unsigned r = u + 0x7fffu + ((u >> 16) & 1u);
  return (unsigned short)(r >> 16);
}
__device__ __forceinline__ float bf16_to_f(unsigned short h) {
  return __uint_as_float(((unsigned)h) << 16);
}

// ---------------- preprocess: edge lists + factored spline basis ----------------
// edge record: float4 { bitcast(m*576 + k0c*64), fx, fy, 1.0 }  (ushort base into
// hwbf[b]; w=1 marks valid; zero records give all-zero tap weights and base 0)
__global__ __launch_bounds__(512) void preprocess_kernel(
    const float* __restrict__ adj, const float* __restrict__ coord,
    float4* __restrict__ edge, int* __restrict__ cnt_out,
    float* __restrict__ deginv_out) {
  int row = blockIdx.x;          // b*N + n
  int b = row >> 9;
  int tid = threadIdx.x;         // == m (within batch)
  int lane = tid & 63, wave = tid >> 6;
  __shared__ int wcnt[8];
  float a = adj[(size_t)row * N_ + tid];
  bool flag = (a != 0.0f);
  unsigned long long ball = __ballot(flag);
  if (lane == 0) wcnt[wave] = __popcll(ball);
  __syncthreads();
  int woff = 0, total = 0;
  #pragma unroll
  for (int i = 0; i < 8; ++i) { int c = wcnt[i]; if (i < wave) woff += c; total += c; }
  if (flag) {
    int pos = woff + __popcll(ball & ((1ULL << lane) - 1));
    if (pos < CAP) {
      int m = tid;
      float cxn = coord[(size_t)row * 2 + 0];
      float cyn = coord[(size_t)row * 2 + 1];
      float cxm = coord[(size_t)(b * N_ + m) * 2 + 0];
      float cym = coord[(size_t)(b * N_ + m) * 2 + 1];
      float vx = (cxm - cxn + 1.0f) * 0.5f * 2.0f;
      float vy = (cym - cyn + 1.0f) * 0.5f * 2.0f;
      float i0x = fminf(fmaxf(floorf(vx), 0.0f), 1.0f);
      float i0y = fminf(fmaxf(floorf(vy), 0.0f), 1.0f);
      float fx = vx - i0x, fy = vy - i0y;
      int k0c = (int)i0x * 3 + (int)i0y;
      int ebase = m * HWC + k0c * F_;   // ushort index into hwbf[b]
      edge[(size_t)row * CAP + pos] =
          make_float4(__int_as_float(ebase), fx, fy, 1.0f);
    }
  }
  if (tid == 0) {
    cnt_out[row] = total > CAP ? CAP : total;
    deginv_out[row] = 1.0f / (float)(total > 0 ? total : 1);
  }
}

// ---------------- convert x (fp32 [M,128]) -> split-bf16 A [M, 384] ----------------
__global__ void convx_kernel(const float* __restrict__ x, unsigned short* __restrict__ a) {
  int idx = blockIdx.x * blockDim.x + threadIdx.x;
  if (idx >= B_ * N_ * 128) return;
  int row = idx >> 7, k = idx & 127;
  float v = x[idx];
  unsigned short hi = to_bf16_rne(v);
  unsigned short lo = to_bf16_rne(v - bf16_to_f(hi));
  size_t base = (size_t)row * 384;
  a[base + k] = hi;
  a[base + 128 + k] = lo;
  a[base + 256 + k] = hi;
}

// ---- pack w (9 slices)+root -> W^T split-bf16 [640 n][3*cin k'] (slabs hi,hi,lo) ----
__global__ void packw_kernel(const float* __restrict__ w, const float* __restrict__ root,
                             int cin, unsigned short* __restrict__ wt) {
  int idx = blockIdx.x * blockDim.x + threadIdx.x;
  int total = NCOL * cin;
  if (idx >= total) return;
  int n = idx / cin, k = idx - n * cin;
  int kk = n >> 6, f = n & 63;
  float v = (kk < 9) ? w[((size_t)kk * cin + k) * F_ + f]
                     : root[(size_t)k * F_ + f];
  unsigned short hi = to_bf16_rne(v);
  unsigned short lo = to_bf16_rne(v - bf16_to_f(hi));
  size_t base = (size_t)n * (3 * cin);
  wt[base + k] = hi;
  wt[base + cin + k] = hi;
  wt[base + 2 * cin + k] = lo;
}

// ---------------- split-bf16 MFMA GEMM -> bf16 hw + fp32 root ----------------
// 128x128 tile, 256 threads = 4 waves (2x2 of 64x64), 16x16x32 bf16 MFMA, BK=64.
// LDS rows padded +8 bf16 (stride 144B -> conflict-free b128 frag reads).
// Epilogue: kk=(bn+nw)>>6 is wave-uniform; spline cols (kk<9) -> bf16 hwbf
// (contiguous-lane ushort stores), root col block (kk==9) -> fp32 hwroot.
#define BK 64
#define LDK (BK + 8)
__global__ __launch_bounds__(256) void gemm_mfma_kernel(
    const unsigned short* __restrict__ A,   // [M][KP]
    const unsigned short* __restrict__ Wt,  // [640][KP]  (W^T, n-major)
    unsigned short* __restrict__ hwbf,      // [M][576] bf16
    float* __restrict__ hwroot,             // [M][64] fp32
    int KP) {
  __shared__ unsigned short As[128 * LDK];
  __shared__ unsigned short Ws[128 * LDK];
  int bm = blockIdx.x * 128;
  int bn = blockIdx.y * 128;
  int tid = threadIdx.x;
  int wave = tid >> 6, lane = tid & 63;
  int mw = (wave & 1) * 64, nw = (wave >> 1) * 64;
  int lr = lane & 15, quad = lane >> 4;

  f32x4 acc[4][4] = {};
  for (int k0 = 0; k0 < KP; k0 += BK) {
    #pragma unroll
    for (int i = 0; i < 4; ++i) {
      int c = tid + i * 256;            // 0..1023 chunks of 16B
      int row = c >> 3, ck = (c & 7) * 8;
      *(float4*)&As[row * LDK + ck] =
          *(const float4*)&A[(size_t)(bm + row) * KP + k0 + ck];
      *(float4*)&Ws[row * LDK + ck] =
          *(const float4*)&Wt[(size_t)(bn + row) * KP + k0 + ck];
    }
    __syncthreads();
    #pragma unroll
    for (int kk = 0; kk < BK; kk += 32) {
      bf16x8 af[4], bf[4];
      #pragma unroll
      for (int i = 0; i < 4; ++i)
        af[i] = *(const bf16x8*)&As[(mw + 16 * i + lr) * LDK + kk + quad * 8];
      #pragma unroll
      for (int j = 0; j < 4; ++j)
        bf[j] = *(const bf16x8*)&Ws[(nw + 16 * j + lr) * LDK + kk + quad * 8];
      #pragma unroll
      for (int i = 0; i < 4; ++i)
        #pragma unroll
        for (int j = 0; j < 4; ++j)
          acc[i][j] = __builtin_amdgcn_mfma_f32_16x16x32_bf16(af[i], bf[j], acc[i][j], 0, 0, 0);
    }
    __syncthreads();
  }
  // epilogue: C/D layout col=lane&15, row=quad*4+reg (m89-verified).
  // kk = (bn+nw)>>6 uniform across wave (bn+nw mult of 64, 16j+lr < 64).
  int kku = (bn + nw) >> 6;
  if (kku < 9) {
    #pragma unroll
    for (int i = 0; i < 4; ++i)
      #pragma unroll
      for (int j = 0; j < 4; ++j)
        #pragma unroll
        for (int r = 0; r < 4; ++r) {
          int m = bm + mw + 16 * i + quad * 4 + r;
          int n = bn + nw + 16 * j + lr;            // 64*kku .. 64*kku+63
          hwbf[(size_t)m * HWC + n] = to_bf16_rne(acc[i][j][r]);
        }
  } else {
    #pragma unroll
    for (int i = 0; i < 4; ++i)
      #pragma unroll
      for (int j = 0; j < 4; ++j)
        #pragma unroll
        for (int r = 0; r < 4; ++r) {
          int m = bm + mw + 16 * i + quad * 4 + r;
          int f = 16 * j + lr;
          hwroot[(size_t)m * F_ + f] = acc[i][j][r];
        }
  }
}

// ---------------- sparse aggregate (bf16 hw taps) ----------------
// 256 threads = 4 waves, one row per wave. XCD-swizzled (blockIdx&7 = XCD).
// Edge lists staged to LDS, padded to x8 with zero records.
// Per edge: 4 ushort taps (each wave-contiguous 128B); x8 unroll = 32 in flight.
__global__ __launch_bounds__(256) void aggregate_kernel(
    const unsigned short* __restrict__ hwbf,
    const float* __restrict__ hwroot,
    const float4* __restrict__ edge,
    const int* __restrict__ cnt, const float* __restrict__ deginv,
    const float* __restrict__ bias,
    unsigned short* __restrict__ aout,
    unsigned int* __restrict__ gmax) {
  __shared__ float4 esh[4][CAP];
  int wave = threadIdx.x >> 6;
  int f = threadIdx.x & 63;
  int xcd = blockIdx.x & 7;
  int j = blockIdx.x >> 3;
  int b = xcd * 4 + (j >> 7);
  int row = b * N_ + ((j & 127) << 2) + wave;
  int c = cnt[row];
  int cpad = (c + 7) & ~7;
  size_t ebase = (size_t)row * CAP;
  for (int i = f; i < cpad; i += 64)
    esh[wave][i] = (i < c) ? edge[ebase + i] : make_float4(0.f, 0.f, 0.f, 0.f);
  __syncthreads();

  const unsigned short* pb = hwbf + (size_t)b * (N_ * HWC) + f;
  float accs[4] = {0.f, 0.f, 0.f, 0.f};
  for (int e0 = 0; e0 < cpad; e0 += 8) {
    int off[8];
    float w00[8], w01[8], w10[8], w11[8];
    #pragma unroll
    for (int q = 0; q < 8; ++q) {
      float4 er = esh[wave][e0 + q];
      off[q] = __float_as_int(er.x);
      float bx1 = er.y, by1 = er.z, v = er.w;
      float bx0 = v - bx1, by0 = v - by1;
      w00[q] = bx0 * by0; w01[q] = bx0 * by1;
      w10[q] = bx1 * by0; w11[q] = bx1 * by1;
    }
    unsigned short s0[8], s1[8], s2[8], s3[8];
    #pragma unroll
    for (int q = 0; q < 8; ++q) {
      const unsigned short* p = pb + off[q];
      s0[q] = p[0]; s1[q] = p[F_]; s2[q] = p[3 * F_]; s3[q] = p[4 * F_];
    }
    #pragma unroll
    for (int q = 0; q < 8; ++q) {
      float t0 = bf16_to_f(s0[q]), t1 = bf16_to_f(s1[q]);
      float t2 = bf16_to_f(s2[q]), t3 = bf16_to_f(s3[q]);
      accs[q & 3] += w00[q] * t0 + w01[q] * t1 + w10[q] * t2 + w11[q] * t3;
    }
  }
  float di = deginv[row];
  float rootv = hwroot[(size_t)row * F_ + f];
  float val = fmaxf(((accs[0] + accs[1]) + (accs[2] + accs[3])) * di + rootv + bias[f], 0.0f);
  if (aout) {
    unsigned short hi = to_bf16_rne(val);
    unsigned short lo = to_bf16_rne(val - bf16_to_f(hi));
    size_t base = (size_t)row * 192;
    aout[base + f] = hi;
    aout[base + 64 + f] = lo;
    aout[base + 128 + f] = hi;
  }
  if (gmax) {
    // relu output >= 0 -> IEEE bits monotone under unsigned compare
    atomicMax(&gmax[b * F_ + f], __float_as_uint(val));
  }
}

// ---------------- zero the pooled-max buffer ----------------
__global__ void zerog_kernel(unsigned int* __restrict__ g) {
  int i = blockIdx.x * blockDim.x + threadIdx.x;
  if (i < B_ * F_) g[i] = 0u;
}

// ---------------- FC from pooled features ----------------
__global__ __launch_bounds__(64) void fc_kernel(
    const float* __restrict__ g, const float* __restrict__ fcw,
    const float* __restrict__ fcb, float* __restrict__ out) {
  int b = blockIdx.x;
  int f = threadIdx.x;
  __shared__ float gs[64];
  gs[f] = g[b * F_ + f];
  __syncthreads();
  if (f < 10) {
    float s = fcb[f];
    #pragma unroll
    for (int c = 0; c < 64; ++c) s += gs[c] * fcw[c * 10 + f];
    out[b * 10 + f] = s;
  }
}

extern "C" void kernel_launch(void* const* d_in, const int* in_sizes, int n_in,
                              void* d_out, int out_size, void* d_ws, size_t ws_size,
                              hipStream_t stream) {
  const float* x     = (const float*)d_in[0];
  const float* coord = (const float*)d_in[1];
  const float* adj   = (const float*)d_in[2];
  const float* w0    = (const float*)d_in[3];
  const float* root0 = (const float*)d_in[4];
  const float* b0    = (const float*)d_in[5];
  const float* w1    = (const float*)d_in[6];
  const float* root1 = (const float*)d_in[7];
  const float* b1    = (const float*)d_in[8];
  const float* w2    = (const float*)d_in[9];
  const float* root2 = (const float*)d_in[10];
  const float* b2    = (const float*)d_in[11];
  const float* fcw   = (const float*)d_in[12];
  const float* fcb   = (const float*)d_in[13];
  float* out = (float*)d_out;

  char* ws = (char*)d_ws;
  size_t off = 0;
  auto alloc = [&](size_t bytes) {
    void* p = ws + off;
    off = (off + bytes + 255) & ~(size_t)255;
    return p;
  };
  const int R = B_ * N_;  // 16384
  float4* edge    = (float4*)alloc((size_t)R * CAP * 16);
  int*    cnt     = (int*)   alloc((size_t)R * 4);
  float*  deginv  = (float*) alloc((size_t)R * 4);
  unsigned short* abf0 = (unsigned short*)alloc((size_t)R * 384 * 2);
  unsigned short* abfN = (unsigned short*)alloc((size_t)R * 192 * 2);
  unsigned short* wt   = (unsigned short*)alloc((size_t)NCOL * 384 * 2);
  unsigned short* hwbf = (unsigned short*)alloc((size_t)R * HWC * 2);
  float*  hwroot  = (float*) alloc((size_t)R * F_ * 4);
  unsigned int* gmax = (unsigned int*)alloc((size_t)B_ * F_ * 4);

  preprocess_kernel<<<R, 512, 0, stream>>>(adj, coord, edge, cnt, deginv);
  zerog_kernel<<<(B_ * F_ + 255) / 256, 256, 0, stream>>>(gmax);
  convx_kernel<<<(R * 128 + 255) / 256, 256, 0, stream>>>(x, abf0);

  // layer 0 (Cin=128, KP=384)
  packw_kernel<<<(NCOL * 128 + 255) / 256, 256, 0, stream>>>(w0, root0, 128, wt);
  gemm_mfma_kernel<<<dim3(R / 128, NCOL / 128), 256, 0, stream>>>(abf0, wt, hwbf, hwroot, 384);
  aggregate_kernel<<<R / 4, 256, 0, stream>>>(hwbf, hwroot, edge, cnt, deginv, b0, abfN, nullptr);

  // layer 1 (Cin=64, KP=192)
  packw_kernel<<<(NCOL * 64 + 255) / 256, 256, 0, stream>>>(w1, root1, 64, wt);
  gemm_mfma_kernel<<<dim3(R / 128, NCOL / 128), 256, 0, stream>>>(abfN, wt, hwbf, hwroot, 192);
  aggregate_kernel<<<R / 4, 256, 0, stream>>>(hwbf, hwroot, edge, cnt, deginv, b1, abfN, nullptr);

  // layer 2 (Cin=64, KP=192) — fused max-pool
  packw_kernel<<<(NCOL * 64 + 255) / 256, 256, 0, stream>>>(w2, root2, 64, wt);
  gemm_mfma_kernel<<<dim3(R / 128, NCOL / 128), 256, 0, stream>>>(abfN, wt, hwbf, hwroot, 192);
  aggregate_kernel<<<R / 4, 256, 0, stream>>>(hwbf, hwroot, edge, cnt, deginv, b2, nullptr, gmax);

  fc_kernel<<<B_, 64, 0, stream>>>((const float*)gmax, fcw, fcb, out);
}